// Round 1
// baseline (494.222 us; speedup 1.0000x reference)
//
#include <hip/hip_runtime.h>

// Problem constants (from reference setup_inputs)
#define B_   4
#define H_   64
#define W_   2650
#define C_   64
#define N_   680000
#define THR_ 0.5f
#define HW_  (H_ * W_)          // 169600
#define W16_ 166                // ceil(W/16): 64B-line columns
#define M2_  (B_ * H_ * W16_)   // 42496 line-bins == 166 * 256 exactly
#define NB2_ (M2_ / 256)        // 166 zero blocks
#define SEG_ 166                // M2_ / 256: ints per thread in fused scan

// ---- counting-sort by (b, r, c>>4): all points in a bin share the exact
// ---- same 64 feature cache lines (one per channel). ----------------------

__global__ void zero_kernel(int* __restrict__ p) {
    p[blockIdx.x * 256 + threadIdx.x] = 0;       // grid == NB2_ blocks
}

__device__ __forceinline__ int bin_of(const float* pts, const int* ri, int i) {
    int b = (int)pts[(size_t)i * 5];
    int r = ri[i * 2];
    int c = ri[i * 2 + 1];
    return (b * H_ + r) * W16_ + (c >> 4);
}

__global__ void hist_kernel(const float* __restrict__ pts,
                            const int* __restrict__ ri,
                            int* __restrict__ binarr) {
    int i = blockIdx.x * 256 + threadIdx.x;
    if (i >= N_) return;
    atomicAdd(&binarr[bin_of(pts, ri, i)], 1);
}

// Single-block fused exclusive scan of all M2_ bins (replaces scan1+2+3).
// 256 threads x SEG_ contiguous ints each; binarr is 170 KB -> L2-resident.
__global__ void scan_fused_kernel(int* __restrict__ binarr) {
    __shared__ int lds[256];
    const int t = threadIdx.x;
    const int base = t * SEG_;
    int s = 0;
#pragma unroll 4
    for (int k = 0; k < SEG_; k++) s += binarr[base + k];
    lds[t] = s;
    __syncthreads();
    for (int off = 1; off < 256; off <<= 1) {    // Hillis-Steele inclusive
        int x = (t >= off) ? lds[t - off] : 0;
        __syncthreads();
        lds[t] += x;
        __syncthreads();
    }
    int run = lds[t] - s;                        // exclusive prefix of segment
#pragma unroll 4
    for (int k = 0; k < SEG_; k++) {
        int v = binarr[base + k];
        binarr[base + k] = run;                  // exclusive, in place
        run += v;
    }
}

// Assign each point its sorted slot; pack {pt, c&15, mask} into the record so
// the gather kernel never touches ri or seg.
__global__ void scatter_kernel(const float* __restrict__ pts,
                               const int* __restrict__ ri,
                               const float* __restrict__ seg,
                               int* __restrict__ binarr,
                               int* __restrict__ perm) {
    int i = blockIdx.x * 256 + threadIdx.x;
    if (i >= N_) return;
    int b   = (int)pts[(size_t)i * 5];
    int r   = ri[i * 2];
    int c   = ri[i * 2 + 1];
    int bin = (b * H_ + r) * W16_ + (c >> 4);
    int m   = (seg[(size_t)b * HW_ + r * W_ + c] >= THR_) ? 1 : 0;
    int slot = atomicAdd(&binarr[bin], 1);
    perm[slot] = i | ((c & 15) << 20) | (m << 24);   // N < 2^20
}

// ---- main gather: one wave per bin, feat lines pinned in LDS -------------
// lane = channel. Lane ch stages feat[b][ch][r][col0..col0+15] once into its
// own LDS row (written & read by the same lane -> no barrier).
// LATENCY FIX vs previous version: the per-point serial scalar load of
// perm[p] (and the per-point pts[] gather) were the critical path (~16 x
// ~400cy dependent chain per wave -> 2.3 TB/s). Now up to 64 perm records
// are fetched with ONE coalesced vector load (issued before feat staging so
// the latencies overlap) and broadcast via __shfl; point attrs are staged
// cooperatively into LDS in 1-2 parallel rounds. The inner loop has no
// dependent global loads at all.
__global__ __launch_bounds__(256) void gather_kernel(
    const float* __restrict__ pts,       // [N,5]
    const float* __restrict__ feat,      // [B,C,H,W]
    const int*   __restrict__ binarr,    // [M2_] post-scatter inclusive ends
    const int*   __restrict__ perm,      // [N] packed records
    float* __restrict__ out,             // [N,69]
    float* __restrict__ mask_out)        // [N]
{
    __shared__ float lds[4][64 * 17];    // pad 17: inner read = 2 lanes/bank (free)
    __shared__ float alds[4][64 * 5];    // staged point attrs for one chunk
    const int lane  = threadIdx.x & 63;
    const int wslot = threadIdx.x >> 6;
    const int bin   = blockIdx.x * 4 + wslot;   // grid == M2_/4 exactly

    const int end   = binarr[bin];
    const int start = (bin == 0) ? 0 : binarr[bin - 1];
    if (start == end) return;                   // wave-uniform

    const int b    = bin / (H_ * W16_);
    const int rem  = bin % (H_ * W16_);
    const int r    = rem / W16_;
    const int col0 = (rem % W16_) * 16;

    // Issue the first perm chunk BEFORE feat staging: both latencies overlap.
    int cnt = min(end - start, 64);
    int rec_l = (lane < cnt) ? perm[start + lane] : 0;

    const size_t fbase = (size_t)(b * C_ + lane) * HW_ + (size_t)r * W_ + col0;
    float* dst = &lds[wslot][lane * 17];
    if (col0 + 16 <= W_) {
        // HW_, W_, col0 all even -> 8 B aligned
        const float2* s2 = (const float2*)(feat + fbase);
#pragma unroll
        for (int j = 0; j < 8; j++) {
            float2 v = s2[j];
            dst[2 * j] = v.x;
            dst[2 * j + 1] = v.y;
        }
    } else {                                    // edge bin: clamp (dups unused)
#pragma unroll
        for (int j = 0; j < 16; j++) {
            int col = col0 + j;
            if (col >= W_) col = W_ - 1;
            dst[j] = feat[(size_t)(b * C_ + lane) * HW_ + (size_t)r * W_ + col];
        }
    }

    float* arow = alds[wslot];
    int p0 = start;
    for (;;) {
        // Cooperative attr staging: cnt*5 floats, all lanes load in parallel.
        // __shfl executed by ALL lanes (uniform loop bound), store predicated,
        // source index clamped into [0,cnt) so only live lanes are read.
        const int na = cnt * 5;
        for (int rbase = 0; rbase < na; rbase += 64) {
            int idx = rbase + lane;
            int pj  = idx / 5;                  // magic-mul, no div unit
            int a   = idx - pj * 5;
            int pjc = (idx < na) ? pj : 0;
            int ptj = __shfl(rec_l, pjc) & 0xFFFFF;
            if (idx < na) arow[idx] = pts[(size_t)ptj * 5 + a];
        }
        // single-wave producer/consumer: compiler-inserted waitcnts suffice
#pragma unroll 4
        for (int j = 0; j < cnt; j++) {
            const int rec = __shfl(rec_l, j);   // broadcast, no memory
            const int pt  = rec & 0xFFFFF;
            const float m = (float)((rec >> 24) & 1);
            const float f = dst[(rec >> 20) & 15];
            const size_t orow = (size_t)pt * 69;
            out[orow + 5 + lane] = f * m;       // 256 B contiguous store
            if (lane < 5) out[orow + lane] = arow[j * 5 + lane] * m;
            if (lane == 0) mask_out[pt] = m;
        }
        p0 += cnt;
        if (p0 >= end) break;
        cnt = min(end - p0, 64);
        rec_l = (lane < cnt) ? perm[p0 + lane] : 0;
    }
}

// ---- fallback (identity order, from R1) — only if ws too small -----------
__global__ __launch_bounds__(256) void gather_fallback(
    const float* __restrict__ pts, const int* __restrict__ ri,
    const float* __restrict__ seg, const float* __restrict__ feat,
    float* __restrict__ out, float* __restrict__ mask_out)
{
    const int lane = threadIdx.x & 63;
    const int pt   = blockIdx.x * 4 + (threadIdx.x >> 6);
    if (pt >= N_) return;
    int b = (int)pts[(size_t)pt * 5];
    int r = ri[pt * 2], c = ri[pt * 2 + 1];
    int rc = r * W_ + c;
    float m = (seg[b * HW_ + rc] >= THR_) ? 1.0f : 0.0f;
    float f = feat[(size_t)b * (C_ * HW_) + (size_t)lane * HW_ + rc];
    size_t orow = (size_t)pt * 69;
    out[orow + 5 + lane] = f * m;
    if (lane < 5) out[orow + lane] = pts[(size_t)pt * 5 + lane] * m;
    if (lane == 0) mask_out[pt] = m;
}

// ---- launch --------------------------------------------------------------

extern "C" void kernel_launch(void* const* d_in, const int* in_sizes, int n_in,
                              void* d_out, int out_size, void* d_ws, size_t ws_size,
                              hipStream_t stream) {
    const float* points = (const float*)d_in[0];
    const int*   ri     = (const int*)  d_in[1];
    const float* seg    = (const float*)d_in[2];
    const float* feat   = (const float*)d_in[3];

    float* out      = (float*)d_out;                       // N*69
    float* mask_out = (float*)d_out + (size_t)N_ * 69;     // N

    // Workspace layout (ints): binarr[M2_] | perm[N_]  ~2.9 MB
    int* binarr = (int*)d_ws;
    int* perm   = binarr + M2_;
    const size_t needed = ((size_t)M2_ + N_) * sizeof(int);
    const bool use_sort = (ws_size >= needed);   // ws_size constant -> replay-safe

    const int nblkN = (N_ + 255) / 256;

    if (use_sort) {
        zero_kernel     <<<NB2_,   256, 0, stream>>>(binarr);
        hist_kernel     <<<nblkN,  256, 0, stream>>>(points, ri, binarr);
        scan_fused_kernel<<<1,     256, 0, stream>>>(binarr);
        scatter_kernel  <<<nblkN,  256, 0, stream>>>(points, ri, seg, binarr, perm);
        gather_kernel   <<<M2_ / 4, 256, 0, stream>>>(points, feat, binarr, perm,
                                                      out, mask_out);
    } else {
        gather_fallback<<<(N_ + 3) / 4, 256, 0, stream>>>(points, ri, seg, feat,
                                                          out, mask_out);
    }
}

// Round 2
// 471.761 us; speedup vs baseline: 1.0476x; 1.0476x over previous
//
#include <hip/hip_runtime.h>

// Problem constants (from reference setup_inputs)
#define B_   4
#define H_   64
#define W_   2650
#define C_   64
#define N_   680000
#define THR_ 0.5f
#define HW_  (H_ * W_)          // 169600
#define W16_ 166                // ceil(W/16): 64B-line columns
#define M2_  (B_ * H_ * W16_)   // 42496 line-bins == 166 * 256 exactly
#define NB2_ (M2_ / 256)        // 166 scan blocks
#define W32_ 83                 // ceil(W/32): 128B windows (2 bins each)
#define M32_ (B_ * H_ * W32_)   // 21248 windows == M2_/2

// ---- counting-sort by (b, r, c>>4): all points in a bin share the exact
// ---- same 64 feature cache lines (one per channel). Gather consumes bins
// ---- in PAIRS (128B contiguous per channel) for HBM burst efficiency. ----

__global__ void zero_kernel(int* __restrict__ p) {
    p[blockIdx.x * 256 + threadIdx.x] = 0;       // grid == NB2_ blocks
}

__global__ void hist_kernel(const float* __restrict__ pts,
                            const int* __restrict__ ri,
                            int* __restrict__ binarr) {
    int i = blockIdx.x * 256 + threadIdx.x;
    if (i >= N_) return;
    int b = (int)pts[(size_t)i * 5];
    int2 rc = ((const int2*)ri)[i];
    atomicAdd(&binarr[(b * H_ + rc.x) * W16_ + (rc.y >> 4)], 1);
}

// In-place per-block exclusive scan; block totals -> bsum. (3-kernel parallel
// scan: the 1-block fused variant serialized the graph and cost ~30 µs.)
__global__ void scan1_kernel(int* __restrict__ binarr, int* __restrict__ bsum) {
    __shared__ int lds[256];
    int t = threadIdx.x;
    int g = blockIdx.x * 256 + t;
    int v = binarr[g];
    lds[t] = v;
    __syncthreads();
    for (int off = 1; off < 256; off <<= 1) {    // Hillis-Steele inclusive
        int x = (t >= off) ? lds[t - off] : 0;
        __syncthreads();
        lds[t] += x;
        __syncthreads();
    }
    binarr[g] = lds[t] - v;                      // exclusive, in place
    if (t == 255) bsum[blockIdx.x] = lds[255];
}

__global__ void scan2_kernel(int* __restrict__ bsum) {
    __shared__ int lds[256];
    int t = threadIdx.x;
    int v = (t < NB2_) ? bsum[t] : 0;
    lds[t] = v;
    __syncthreads();
    for (int off = 1; off < 256; off <<= 1) {
        int x = (t >= off) ? lds[t - off] : 0;
        __syncthreads();
        lds[t] += x;
        __syncthreads();
    }
    if (t < NB2_) bsum[t] = lds[t] - v;          // exclusive
}

__global__ void scan3_kernel(int* __restrict__ binarr, const int* __restrict__ bsum) {
    int g = blockIdx.x * 256 + threadIdx.x;      // grid == NB2_ blocks
    binarr[g] += bsum[blockIdx.x];
}

// Assign each point its sorted slot; pack {pt, c&31, mask} into the record so
// the gather kernel never touches ri or seg. (c&31: gather windows are 32
// columns = 2 bins wide.)
__global__ void scatter_kernel(const float* __restrict__ pts,
                               const int* __restrict__ ri,
                               const float* __restrict__ seg,
                               int* __restrict__ binarr,
                               int* __restrict__ perm) {
    int i = blockIdx.x * 256 + threadIdx.x;
    if (i >= N_) return;
    int b   = (int)pts[(size_t)i * 5];
    int2 rc = ((const int2*)ri)[i];
    int r = rc.x, c = rc.y;
    int bin = (b * H_ + r) * W16_ + (c >> 4);
    int m   = (seg[(size_t)b * HW_ + r * W_ + c] >= THR_) ? 1 : 0;
    int slot = atomicAdd(&binarr[bin], 1);
    perm[slot] = i | ((c & 31) << 20) | (m << 25);   // N < 2^20
}

// ---- main gather: one wave per 32-col WINDOW (2 adjacent bins) -----------
// lane = channel. Lane ch stages feat[b][ch][r][col0..col0+31] (128B
// contiguous -> better HBM burst efficiency than the previous 64B granule)
// into its own LDS row (written & read by the same lane -> no barrier).
// perm records for the window are contiguous (bins 2w,2w+1 adjacent in the
// counting sort); chunks of <=64 are fetched with one coalesced load and
// broadcast via __shfl; point attrs staged cooperatively into LDS so the
// inner loop has no dependent global loads.
__global__ __launch_bounds__(256) void gather_kernel(
    const float* __restrict__ pts,       // [N,5]
    const float* __restrict__ feat,      // [B,C,H,W]
    const int*   __restrict__ binarr,    // [M2_] post-scatter inclusive ends
    const int*   __restrict__ perm,      // [N] packed records
    float* __restrict__ out,             // [N,69]
    float* __restrict__ mask_out)        // [N]
{
    // pad 34: row start 136B (8B-aligned for float2 writes); inner read
    // bank = (lane*2 + x) % 32 -> 2 lanes/bank (free, m136).
    __shared__ float lds[4][64 * 34];
    __shared__ float alds[4][64 * 5];    // staged point attrs for one chunk
    const int lane  = threadIdx.x & 63;
    const int wslot = threadIdx.x >> 6;
    const int win   = blockIdx.x * 4 + wslot;   // grid == M32_/4 exactly

    const int end   = binarr[2 * win + 1];
    const int start = (win == 0) ? 0 : binarr[2 * win - 1];
    if (start == end) return;                   // wave-uniform

    const int b    = win / (H_ * W32_);
    const int rem  = win % (H_ * W32_);
    const int r    = rem / W32_;
    const int col0 = (rem % W32_) * 32;

    // Issue the first perm chunk BEFORE feat staging: latencies overlap.
    int cnt = min(end - start, 64);
    int rec_l = (lane < cnt) ? perm[start + lane] : 0;

    const size_t fbase = (size_t)(b * C_ + lane) * HW_ + (size_t)r * W_ + col0;
    float* dst = &lds[wslot][lane * 34];
    if (col0 + 32 <= W_) {
        // HW_, W_ even, col0 % 32 == 0 -> 8B-aligned source
        const float2* s2 = (const float2*)(feat + fbase);
#pragma unroll
        for (int j = 0; j < 16; j++) {
            float2 v = s2[j];
            dst[2 * j] = v.x;
            dst[2 * j + 1] = v.y;
        }
    } else {                                    // edge window: clamp (dups unused)
#pragma unroll
        for (int j = 0; j < 32; j++) {
            int col = col0 + j;
            if (col >= W_) col = W_ - 1;
            dst[j] = feat[(size_t)(b * C_ + lane) * HW_ + (size_t)r * W_ + col];
        }
    }

    float* arow = alds[wslot];
    int p0 = start;
    for (;;) {
        // Cooperative attr staging: cnt*5 floats, all lanes load in parallel.
        // __shfl executed by ALL lanes (uniform bound), store predicated,
        // source index clamped into [0,cnt) so only live lanes are read.
        const int na = cnt * 5;
        for (int rbase = 0; rbase < na; rbase += 64) {
            int idx = rbase + lane;
            int pj  = idx / 5;                  // magic-mul, no div unit
            int a   = idx - pj * 5;
            int pjc = (idx < na) ? pj : 0;
            int ptj = __shfl(rec_l, pjc) & 0xFFFFF;
            if (idx < na) arow[idx] = pts[(size_t)ptj * 5 + a];
        }
        // single-wave producer/consumer: compiler-inserted waitcnts suffice
#pragma unroll 4
        for (int j = 0; j < cnt; j++) {
            const int rec = __shfl(rec_l, j);   // broadcast, no memory
            const int pt  = rec & 0xFFFFF;
            const float m = (float)((rec >> 25) & 1);
            const float f = dst[(rec >> 20) & 31];
            const size_t orow = (size_t)pt * 69;
            out[orow + 5 + lane] = f * m;       // 256 B contiguous store
            if (lane < 5) out[orow + lane] = arow[j * 5 + lane] * m;
            if (lane == 0) mask_out[pt] = m;
        }
        p0 += cnt;
        if (p0 >= end) break;
        cnt = min(end - p0, 64);
        rec_l = (lane < cnt) ? perm[p0 + lane] : 0;
    }
}

// ---- fallback (identity order) — only if ws too small --------------------
__global__ __launch_bounds__(256) void gather_fallback(
    const float* __restrict__ pts, const int* __restrict__ ri,
    const float* __restrict__ seg, const float* __restrict__ feat,
    float* __restrict__ out, float* __restrict__ mask_out)
{
    const int lane = threadIdx.x & 63;
    const int pt   = blockIdx.x * 4 + (threadIdx.x >> 6);
    if (pt >= N_) return;
    int b = (int)pts[(size_t)pt * 5];
    int r = ri[pt * 2], c = ri[pt * 2 + 1];
    int rc = r * W_ + c;
    float m = (seg[b * HW_ + rc] >= THR_) ? 1.0f : 0.0f;
    float f = feat[(size_t)b * (C_ * HW_) + (size_t)lane * HW_ + rc];
    size_t orow = (size_t)pt * 69;
    out[orow + 5 + lane] = f * m;
    if (lane < 5) out[orow + lane] = pts[(size_t)pt * 5 + lane] * m;
    if (lane == 0) mask_out[pt] = m;
}

// ---- launch --------------------------------------------------------------

extern "C" void kernel_launch(void* const* d_in, const int* in_sizes, int n_in,
                              void* d_out, int out_size, void* d_ws, size_t ws_size,
                              hipStream_t stream) {
    const float* points = (const float*)d_in[0];
    const int*   ri     = (const int*)  d_in[1];
    const float* seg    = (const float*)d_in[2];
    const float* feat   = (const float*)d_in[3];

    float* out      = (float*)d_out;                       // N*69
    float* mask_out = (float*)d_out + (size_t)N_ * 69;     // N

    // Workspace layout (ints): binarr[M2_] | bsum[256] | perm[N_]  ~2.9 MB
    int* binarr = (int*)d_ws;
    int* bsum   = binarr + M2_;
    int* perm   = bsum + 256;
    const size_t needed = ((size_t)M2_ + 256 + N_) * sizeof(int);
    const bool use_sort = (ws_size >= needed);   // ws_size constant -> replay-safe

    const int nblkN = (N_ + 255) / 256;

    if (use_sort) {
        zero_kernel   <<<NB2_,    256, 0, stream>>>(binarr);
        hist_kernel   <<<nblkN,   256, 0, stream>>>(points, ri, binarr);
        scan1_kernel  <<<NB2_,    256, 0, stream>>>(binarr, bsum);
        scan2_kernel  <<<1,       256, 0, stream>>>(bsum);
        scan3_kernel  <<<NB2_,    256, 0, stream>>>(binarr, bsum);
        scatter_kernel<<<nblkN,   256, 0, stream>>>(points, ri, seg, binarr, perm);
        gather_kernel <<<M32_ / 4, 256, 0, stream>>>(points, feat, binarr, perm,
                                                     out, mask_out);
    } else {
        gather_fallback<<<(N_ + 3) / 4, 256, 0, stream>>>(points, ri, seg, feat,
                                                          out, mask_out);
    }
}

// Round 3
// 429.476 us; speedup vs baseline: 1.1508x; 1.0985x over previous
//
#include <hip/hip_runtime.h>

// Problem constants (from reference setup_inputs)
#define B_   4
#define H_   64
#define W_   2650
#define C_   64
#define N_   680000
#define THR_ 0.5f
#define HW_  (H_ * W_)          // 169600
#define W16_ 166                // ceil(W/16): 64B-line columns
#define M2_  (B_ * H_ * W16_)   // 42496 line-bins == 166 * 256 exactly
#define NB2_ (M2_ / 256)        // 166 scan blocks

// ---- counting-sort by (b, r, c>>4), FOREGROUND POINTS ONLY ---------------
// seg test happens in hist/scatter; background rows are produced by a
// streaming pre-zero of the output (full-line-aligned writes at ~6 TB/s)
// instead of per-point scattered zero stores (unmerged partial lines at
// ~1.5 TB/s). This halves gather's inner-loop work and its write traffic.

// Pre-zero out+mask (contiguous N*70 floats). Grid-stride float4.
__global__ void zero_out_kernel(float4* __restrict__ p) {
    const size_t total = (size_t)N_ * 70 / 4;            // 11.9M exactly
    size_t i = (size_t)blockIdx.x * 256 + threadIdx.x;
    const size_t stride = (size_t)gridDim.x * 256;
    const float4 z = {0.f, 0.f, 0.f, 0.f};
    for (; i < total; i += stride) p[i] = z;
}

__global__ void zero_kernel(int* __restrict__ p) {
    p[blockIdx.x * 256 + threadIdx.x] = 0;               // grid == NB2_
}

__global__ void hist_kernel(const float* __restrict__ pts,
                            const int* __restrict__ ri,
                            const float* __restrict__ seg,
                            int* __restrict__ binarr) {
    int i = blockIdx.x * 256 + threadIdx.x;
    if (i >= N_) return;
    int b = (int)pts[(size_t)i * 5];
    int2 rc = ((const int2*)ri)[i];
    if (seg[(size_t)b * HW_ + rc.x * W_ + rc.y] >= THR_)  // fg only
        atomicAdd(&binarr[(b * H_ + rc.x) * W16_ + (rc.y >> 4)], 1);
}

// In-place per-block exclusive scan; block totals -> bsum. (3-kernel
// parallel scan: the 1-block fused variant serialized the graph, ~+30 µs.)
__global__ void scan1_kernel(int* __restrict__ binarr, int* __restrict__ bsum) {
    __shared__ int lds[256];
    int t = threadIdx.x;
    int g = blockIdx.x * 256 + t;
    int v = binarr[g];
    lds[t] = v;
    __syncthreads();
    for (int off = 1; off < 256; off <<= 1) {    // Hillis-Steele inclusive
        int x = (t >= off) ? lds[t - off] : 0;
        __syncthreads();
        lds[t] += x;
        __syncthreads();
    }
    binarr[g] = lds[t] - v;                      // exclusive, in place
    if (t == 255) bsum[blockIdx.x] = lds[255];
}

__global__ void scan2_kernel(int* __restrict__ bsum) {
    __shared__ int lds[256];
    int t = threadIdx.x;
    int v = (t < NB2_) ? bsum[t] : 0;
    lds[t] = v;
    __syncthreads();
    for (int off = 1; off < 256; off <<= 1) {
        int x = (t >= off) ? lds[t - off] : 0;
        __syncthreads();
        lds[t] += x;
        __syncthreads();
    }
    if (t < NB2_) bsum[t] = lds[t] - v;          // exclusive
}

__global__ void scan3_kernel(int* __restrict__ binarr, const int* __restrict__ bsum) {
    int g = blockIdx.x * 256 + threadIdx.x;      // grid == NB2_ blocks
    binarr[g] += bsum[blockIdx.x];
}

// Assign each FG point its sorted slot; pack {pt, c&15}. Background points
// never enter perm (their output rows stay pre-zeroed).
__global__ void scatter_kernel(const float* __restrict__ pts,
                               const int* __restrict__ ri,
                               const float* __restrict__ seg,
                               int* __restrict__ binarr,
                               int* __restrict__ perm) {
    int i = blockIdx.x * 256 + threadIdx.x;
    if (i >= N_) return;
    int b   = (int)pts[(size_t)i * 5];
    int2 rc = ((const int2*)ri)[i];
    int r = rc.x, c = rc.y;
    if (seg[(size_t)b * HW_ + r * W_ + c] < THR_) return;   // fg only
    int bin  = (b * H_ + r) * W16_ + (c >> 4);
    int slot = atomicAdd(&binarr[bin], 1);
    perm[slot] = i | ((c & 15) << 20);           // N < 2^20, c&15 in 20..23
}

// ---- main gather: one wave per bin, feat lines pinned in LDS -------------
// lane = channel. Lane ch stages feat[b][ch][r][col0..col0+15] once into its
// own LDS row (written & read by the same lane -> no barrier). perm chunks
// (<=64 records) fetched with one coalesced load issued BEFORE feat staging
// (latencies overlap) and broadcast via __shfl; point attrs staged
// cooperatively into LDS so the inner loop has no dependent global loads.
// All perm records are foreground: no mask multiply, ~half the points of R1.
__global__ __launch_bounds__(256) void gather_kernel(
    const float* __restrict__ pts,       // [N,5]
    const float* __restrict__ feat,      // [B,C,H,W]
    const int*   __restrict__ binarr,    // [M2_] post-scatter inclusive ends
    const int*   __restrict__ perm,      // [Nfg] packed records
    float* __restrict__ out,             // [N,69] (pre-zeroed)
    float* __restrict__ mask_out)        // [N]    (pre-zeroed)
{
    __shared__ float lds[4][64 * 17];    // pad 17: inner read 2 lanes/bank (free)
    __shared__ float alds[4][64 * 5];    // staged point attrs for one chunk
    const int lane  = threadIdx.x & 63;
    const int wslot = threadIdx.x >> 6;
    const int bin   = blockIdx.x * 4 + wslot;   // grid == M2_/4 exactly

    const int end   = binarr[bin];
    const int start = (bin == 0) ? 0 : binarr[bin - 1];
    if (start == end) return;                   // wave-uniform

    const int b    = bin / (H_ * W16_);
    const int rem  = bin % (H_ * W16_);
    const int r    = rem / W16_;
    const int col0 = (rem % W16_) * 16;

    // Issue the first perm chunk BEFORE feat staging: latencies overlap.
    int cnt = min(end - start, 64);
    int rec_l = (lane < cnt) ? perm[start + lane] : 0;

    const size_t fbase = (size_t)(b * C_ + lane) * HW_ + (size_t)r * W_ + col0;
    float* dst = &lds[wslot][lane * 17];
    if (col0 + 16 <= W_) {
        // HW_, W_, col0 all even -> 8 B aligned
        const float2* s2 = (const float2*)(feat + fbase);
#pragma unroll
        for (int j = 0; j < 8; j++) {
            float2 v = s2[j];
            dst[2 * j] = v.x;
            dst[2 * j + 1] = v.y;
        }
    } else {                                    // edge bin: clamp (dups unused)
#pragma unroll
        for (int j = 0; j < 16; j++) {
            int col = col0 + j;
            if (col >= W_) col = W_ - 1;
            dst[j] = feat[(size_t)(b * C_ + lane) * HW_ + (size_t)r * W_ + col];
        }
    }

    float* arow = alds[wslot];
    int p0 = start;
    for (;;) {
        // Cooperative attr staging: cnt*5 floats, all lanes load in parallel.
        // __shfl executed by ALL lanes (uniform bound), store predicated,
        // source index clamped into [0,cnt) so only live lanes are read.
        const int na = cnt * 5;
        for (int rbase = 0; rbase < na; rbase += 64) {
            int idx = rbase + lane;
            int pj  = idx / 5;                  // magic-mul, no div unit
            int a   = idx - pj * 5;
            int pjc = (idx < na) ? pj : 0;
            int ptj = __shfl(rec_l, pjc) & 0xFFFFF;
            if (idx < na) arow[idx] = pts[(size_t)ptj * 5 + a];
        }
        // single-wave producer/consumer: compiler-inserted waitcnts suffice
#pragma unroll 4
        for (int j = 0; j < cnt; j++) {
            const int rec = __shfl(rec_l, j);   // broadcast, no memory
            const int pt  = rec & 0xFFFFF;
            const float f = dst[(rec >> 20) & 15];
            const size_t orow = (size_t)pt * 69;
            out[orow + 5 + lane] = f;           // 256 B contiguous store
            if (lane < 5) out[orow + lane] = arow[j * 5 + lane];
            if (lane == 0) mask_out[pt] = 1.0f;
        }
        p0 += cnt;
        if (p0 >= end) break;
        cnt = min(end - p0, 64);
        rec_l = (lane < cnt) ? perm[p0 + lane] : 0;
    }
}

// ---- fallback (identity order) — only if ws too small. Writes ALL rows
// ---- (incl. background zeros), so it does not need the pre-zero pass. ----
__global__ __launch_bounds__(256) void gather_fallback(
    const float* __restrict__ pts, const int* __restrict__ ri,
    const float* __restrict__ seg, const float* __restrict__ feat,
    float* __restrict__ out, float* __restrict__ mask_out)
{
    const int lane = threadIdx.x & 63;
    const int pt   = blockIdx.x * 4 + (threadIdx.x >> 6);
    if (pt >= N_) return;
    int b = (int)pts[(size_t)pt * 5];
    int r = ri[pt * 2], c = ri[pt * 2 + 1];
    int rc = r * W_ + c;
    float m = (seg[b * HW_ + rc] >= THR_) ? 1.0f : 0.0f;
    float f = feat[(size_t)b * (C_ * HW_) + (size_t)lane * HW_ + rc];
    size_t orow = (size_t)pt * 69;
    out[orow + 5 + lane] = f * m;
    if (lane < 5) out[orow + lane] = pts[(size_t)pt * 5 + lane] * m;
    if (lane == 0) mask_out[pt] = m;
}

// ---- launch --------------------------------------------------------------

extern "C" void kernel_launch(void* const* d_in, const int* in_sizes, int n_in,
                              void* d_out, int out_size, void* d_ws, size_t ws_size,
                              hipStream_t stream) {
    const float* points = (const float*)d_in[0];
    const int*   ri     = (const int*)  d_in[1];
    const float* seg    = (const float*)d_in[2];
    const float* feat   = (const float*)d_in[3];

    float* out      = (float*)d_out;                       // N*69
    float* mask_out = (float*)d_out + (size_t)N_ * 69;     // N (contiguous)

    // Workspace layout (ints): binarr[M2_] | bsum[256] | perm[N_]  ~2.9 MB
    int* binarr = (int*)d_ws;
    int* bsum   = binarr + M2_;
    int* perm   = bsum + 256;
    const size_t needed = ((size_t)M2_ + 256 + N_) * sizeof(int);
    const bool use_sort = (ws_size >= needed);   // ws_size constant -> replay-safe

    const int nblkN = (N_ + 255) / 256;

    if (use_sort) {
        zero_out_kernel<<<2048,  256, 0, stream>>>((float4*)out);
        zero_kernel   <<<NB2_,   256, 0, stream>>>(binarr);
        hist_kernel   <<<nblkN,  256, 0, stream>>>(points, ri, seg, binarr);
        scan1_kernel  <<<NB2_,   256, 0, stream>>>(binarr, bsum);
        scan2_kernel  <<<1,      256, 0, stream>>>(bsum);
        scan3_kernel  <<<NB2_,   256, 0, stream>>>(binarr, bsum);
        scatter_kernel<<<nblkN,  256, 0, stream>>>(points, ri, seg, binarr, perm);
        gather_kernel <<<M2_ / 4, 256, 0, stream>>>(points, feat, binarr, perm,
                                                    out, mask_out);
    } else {
        gather_fallback<<<(N_ + 3) / 4, 256, 0, stream>>>(points, ri, seg, feat,
                                                          out, mask_out);
    }
}

// Round 4
// 417.757 us; speedup vs baseline: 1.1830x; 1.0281x over previous
//
#include <hip/hip_runtime.h>

// Problem constants (from reference setup_inputs)
#define B_   4
#define H_   64
#define W_   2650
#define C_   64
#define N_   680000
#define THR_ 0.5f
#define HW_  (H_ * W_)          // 169600
#define W16_ 166                // ceil(W/16): 64B-line columns
#define M2_  (B_ * H_ * W16_)   // 42496 line-bins == 166 * 256 exactly
#define NB2_ (M2_ / 256)        // 166 scan blocks
#define SPR_ 21                 // strips per (b,r) row: ceil(166/8), strip = 128 cols
#define NSTRIP_ (B_ * H_ * SPR_)  // 5376 gather blocks
#define ROWF_ 129               // LDS row stride (floats). ODD -> inner read is
                                // (ch + x) % 32 across 64 lanes = 2-way = free.

// ---- counting-sort by (b, r, c>>4), FOREGROUND POINTS ONLY ---------------
// Background rows come from a streaming pre-zero (full-line writes ~6.3TB/s).
// Gather processes 128-column STRIPS per block: feature staging reads 512B
// CONTIGUOUS per channel (vs 64B in R3) for DRAM row-buffer locality, with
// occupancy and LDS-bank confounds of the R2 probe engineered out.

// Fused: zero binarr (blocks 0..NB2_-1) + zero out/mask (remaining blocks).
__global__ void zero_fused_kernel(int* __restrict__ binarr,
                                  float4* __restrict__ outp) {
    const int bid = blockIdx.x;
    if (bid < NB2_) {
        binarr[bid * 256 + threadIdx.x] = 0;
        return;
    }
    const size_t total = (size_t)N_ * 70 / 4;            // out(69) + mask(1)
    size_t i = (size_t)(bid - NB2_) * 256 + threadIdx.x;
    const size_t stride = (size_t)(gridDim.x - NB2_) * 256;
    const float4 z = {0.f, 0.f, 0.f, 0.f};
    for (; i < total; i += stride) outp[i] = z;
}

__global__ void hist_kernel(const float* __restrict__ pts,
                            const int* __restrict__ ri,
                            const float* __restrict__ seg,
                            int* __restrict__ binarr) {
    int i = blockIdx.x * 256 + threadIdx.x;
    if (i >= N_) return;
    int b = (int)pts[(size_t)i * 5];
    int2 rc = ((const int2*)ri)[i];
    if (seg[(size_t)b * HW_ + rc.x * W_ + rc.y] >= THR_)  // fg only
        atomicAdd(&binarr[(b * H_ + rc.x) * W16_ + (rc.y >> 4)], 1);
}

// 3-kernel parallel scan (1-block fused variant serialized the graph, +30µs).
__global__ void scan1_kernel(int* __restrict__ binarr, int* __restrict__ bsum) {
    __shared__ int lds[256];
    int t = threadIdx.x;
    int g = blockIdx.x * 256 + t;
    int v = binarr[g];
    lds[t] = v;
    __syncthreads();
    for (int off = 1; off < 256; off <<= 1) {    // Hillis-Steele inclusive
        int x = (t >= off) ? lds[t - off] : 0;
        __syncthreads();
        lds[t] += x;
        __syncthreads();
    }
    binarr[g] = lds[t] - v;                      // exclusive, in place
    if (t == 255) bsum[blockIdx.x] = lds[255];
}

__global__ void scan2_kernel(int* __restrict__ bsum) {
    __shared__ int lds[256];
    int t = threadIdx.x;
    int v = (t < NB2_) ? bsum[t] : 0;
    lds[t] = v;
    __syncthreads();
    for (int off = 1; off < 256; off <<= 1) {
        int x = (t >= off) ? lds[t - off] : 0;
        __syncthreads();
        lds[t] += x;
        __syncthreads();
    }
    if (t < NB2_) bsum[t] = lds[t] - v;          // exclusive
}

__global__ void scan3_kernel(int* __restrict__ binarr, const int* __restrict__ bsum) {
    int g = blockIdx.x * 256 + threadIdx.x;      // grid == NB2_ blocks
    binarr[g] += bsum[blockIdx.x];
}

// Assign each FG point its sorted slot; pack {pt, c&127} (strip-local col).
__global__ void scatter_kernel(const float* __restrict__ pts,
                               const int* __restrict__ ri,
                               const float* __restrict__ seg,
                               int* __restrict__ binarr,
                               int* __restrict__ perm) {
    int i = blockIdx.x * 256 + threadIdx.x;
    if (i >= N_) return;
    int b   = (int)pts[(size_t)i * 5];
    int2 rc = ((const int2*)ri)[i];
    int r = rc.x, c = rc.y;
    if (seg[(size_t)b * HW_ + r * W_ + c] < THR_) return;   // fg only
    int bin  = (b * H_ + r) * W16_ + (c >> 4);
    int slot = atomicAdd(&binarr[bin], 1);
    perm[slot] = i | ((c & 127) << 20);          // N < 2^20, col in bits 20..26
}

// ---- main gather: one BLOCK per 128-col strip (8 bins) -------------------
// Staging: 64 ch x 512B contiguous per channel (float2, fully coalesced:
// each 64-lane group covers one channel's 512B per instruction). LDS row
// stride 129 floats (odd): inner read bank = (ch + x) % 32 -> 2-way, free.
// 4 waves split the strip's fg-point range; per-wave perm chunks (<=64)
// fetched coalesced + broadcast via __shfl; attrs staged cooperatively.
__global__ __launch_bounds__(256) void gather_kernel(
    const float* __restrict__ pts,       // [N,5]
    const float* __restrict__ feat,      // [B,C,H,W]
    const int*   __restrict__ binarr,    // [M2_] post-scatter inclusive ends
    const int*   __restrict__ perm,      // [Nfg] packed records
    float* __restrict__ out,             // [N,69] (pre-zeroed)
    float* __restrict__ mask_out)        // [N]    (pre-zeroed)
{
    __shared__ float flds[64 * ROWF_];   // 33 KB feature strip
    __shared__ float alds[4][64 * 5];    // per-wave staged point attrs
    const int t    = threadIdx.x;
    const int lane = t & 63;
    const int w    = t >> 6;

    const int sx  = blockIdx.x % SPR_;
    const int tmp = blockIdx.x / SPR_;
    const int r   = tmp & (H_ - 1);
    const int b   = tmp >> 6;

    const int rowbin  = (b * H_ + r) * W16_;
    const int first   = rowbin + sx * 8;
    const int lastbin = rowbin + min(sx * 8 + 8, W16_) - 1;
    const int start   = (first == 0) ? 0 : binarr[first - 1];
    const int end     = binarr[lastbin];
    if (start == end) return;                    // block-uniform

    // per-wave contiguous sub-range of the strip's points
    const int tot = end - start;
    const int q = tot >> 2, rm = tot & 3;
    const int wstart = start + w * q + min(w, rm);
    const int wend   = wstart + q + (w < rm ? 1 : 0);

    // Issue first perm chunk BEFORE staging: latencies overlap.
    int cnt = min(wend - wstart, 64);            // may be 0 for tail waves
    int rec_l = (lane < cnt) ? perm[wstart + lane] : 0;

    // ---- block-cooperative feature staging: 64ch x 128 cols = 32 KB ------
    const int c0 = sx * 128;
    if (c0 + 128 <= W_) {
#pragma unroll
        for (int g = 0; g < 16; g++) {
            const int ch = 4 * g + w;            // each (g,wave) a unique ch
            const int x  = 2 * (lane);           // 0..126, even
            // r*W_, c0, x all even -> 8B-aligned float2
            const float2 v = *(const float2*)(feat + (size_t)(b * C_ + ch) * HW_
                                              + (size_t)r * W_ + c0 + x);
            flds[ch * ROWF_ + x]     = v.x;      // bank (ch+2l)%32: 2-way, free
            flds[ch * ROWF_ + x + 1] = v.y;
        }
    } else {                                     // edge strip (sx==20): clamp
#pragma unroll
        for (int g = 0; g < 16; g++) {
            const int ch = 4 * g + w;
            const int x  = 2 * (lane);
            int c1 = c0 + x;     if (c1 >= W_) c1 = W_ - 1;
            int c2 = c0 + x + 1; if (c2 >= W_) c2 = W_ - 1;
            const size_t base = (size_t)(b * C_ + ch) * HW_ + (size_t)r * W_;
            flds[ch * ROWF_ + x]     = feat[base + c1];
            flds[ch * ROWF_ + x + 1] = feat[base + c2];
        }
    }
    __syncthreads();
    if (wstart >= wend) return;                  // tail waves done after staging

    float* arow = alds[w];
    const float* myrow = &flds[lane * ROWF_];    // lane == channel
    int p0 = wstart;
    for (;;) {
        // Cooperative attr staging: cnt*5 floats, all lanes load in parallel.
        // __shfl executed by ALL lanes (uniform bound), store predicated,
        // source index clamped into [0,cnt) so only live lanes are read.
        const int na = cnt * 5;
        for (int rbase = 0; rbase < na; rbase += 64) {
            int idx = rbase + lane;
            int pj  = idx / 5;                   // magic-mul, no div unit
            int a   = idx - pj * 5;
            int pjc = (idx < na) ? pj : 0;
            int ptj = __shfl(rec_l, pjc) & 0xFFFFF;
            if (idx < na) arow[idx] = pts[(size_t)ptj * 5 + a];
        }
        // single-wave producer/consumer on arow: compiler waitcnts suffice
#pragma unroll 4
        for (int j = 0; j < cnt; j++) {
            const int rec = __shfl(rec_l, j);    // broadcast, no memory
            const int pt  = rec & 0xFFFFF;
            const float f = myrow[(rec >> 20) & 127];
            const size_t orow = (size_t)pt * 69;
            out[orow + 5 + lane] = f;            // 256 B contiguous store
            if (lane < 5) out[orow + lane] = arow[j * 5 + lane];
            if (lane == 0) mask_out[pt] = 1.0f;
        }
        p0 += cnt;
        if (p0 >= wend) break;
        cnt = min(wend - p0, 64);
        rec_l = (lane < cnt) ? perm[p0 + lane] : 0;
    }
}

// ---- fallback (identity order) — only if ws too small. Writes ALL rows. --
__global__ __launch_bounds__(256) void gather_fallback(
    const float* __restrict__ pts, const int* __restrict__ ri,
    const float* __restrict__ seg, const float* __restrict__ feat,
    float* __restrict__ out, float* __restrict__ mask_out)
{
    const int lane = threadIdx.x & 63;
    const int pt   = blockIdx.x * 4 + (threadIdx.x >> 6);
    if (pt >= N_) return;
    int b = (int)pts[(size_t)pt * 5];
    int r = ri[pt * 2], c = ri[pt * 2 + 1];
    int rc = r * W_ + c;
    float m = (seg[b * HW_ + rc] >= THR_) ? 1.0f : 0.0f;
    float f = feat[(size_t)b * (C_ * HW_) + (size_t)lane * HW_ + rc];
    size_t orow = (size_t)pt * 69;
    out[orow + 5 + lane] = f * m;
    if (lane < 5) out[orow + lane] = pts[(size_t)pt * 5 + lane] * m;
    if (lane == 0) mask_out[pt] = m;
}

// ---- launch --------------------------------------------------------------

extern "C" void kernel_launch(void* const* d_in, const int* in_sizes, int n_in,
                              void* d_out, int out_size, void* d_ws, size_t ws_size,
                              hipStream_t stream) {
    const float* points = (const float*)d_in[0];
    const int*   ri     = (const int*)  d_in[1];
    const float* seg    = (const float*)d_in[2];
    const float* feat   = (const float*)d_in[3];

    float* out      = (float*)d_out;                       // N*69
    float* mask_out = (float*)d_out + (size_t)N_ * 69;     // N (contiguous)

    // Workspace layout (ints): binarr[M2_] | bsum[256] | perm[N_]  ~2.9 MB
    int* binarr = (int*)d_ws;
    int* bsum   = binarr + M2_;
    int* perm   = bsum + 256;
    const size_t needed = ((size_t)M2_ + 256 + N_) * sizeof(int);
    const bool use_sort = (ws_size >= needed);   // ws_size constant -> replay-safe

    const int nblkN = (N_ + 255) / 256;

    if (use_sort) {
        zero_fused_kernel<<<NB2_ + 2048, 256, 0, stream>>>(binarr, (float4*)out);
        hist_kernel   <<<nblkN,  256, 0, stream>>>(points, ri, seg, binarr);
        scan1_kernel  <<<NB2_,   256, 0, stream>>>(binarr, bsum);
        scan2_kernel  <<<1,      256, 0, stream>>>(bsum);
        scan3_kernel  <<<NB2_,   256, 0, stream>>>(binarr, bsum);
        scatter_kernel<<<nblkN,  256, 0, stream>>>(points, ri, seg, binarr, perm);
        gather_kernel <<<NSTRIP_, 256, 0, stream>>>(points, feat, binarr, perm,
                                                    out, mask_out);
    } else {
        gather_fallback<<<(N_ + 3) / 4, 256, 0, stream>>>(points, ri, seg, feat,
                                                          out, mask_out);
    }
}